// Round 2
// baseline (541.955 us; speedup 1.0000x reference)
//
#include <hip/hip_runtime.h>
#include <hip/hip_bf16.h>

typedef __attribute__((ext_vector_type(8))) short bf16x8;
typedef __attribute__((ext_vector_type(4))) float f32x4;
typedef __attribute__((ext_vector_type(8))) unsigned short u16x8;

__device__ __forceinline__ unsigned short f2b(float f) {
    unsigned u = __builtin_bit_cast(unsigned, f);
    u += 0x7FFFu + ((u >> 16) & 1u);
    return (unsigned short)(u >> 16);
}

__global__ void cast_x_kernel(const float* __restrict__ low, unsigned short* __restrict__ dst) {
    int idx = blockIdx.x * 256 + threadIdx.x;
    if (idx >= 4096 * 608) return;
    int b = idx / 608, k = idx - b * 608;
    dst[idx] = f2b(k < 600 ? low[b * 600 + k] : 0.f);
}

__global__ void cast_pad_w_kernel(const float* __restrict__ src, unsigned short* __restrict__ dst,
                                  int K, int N, int Npad, int total) {
    int idx = blockIdx.x * 256 + threadIdx.x;
    if (idx >= total) return;
    int k = idx / Npad, n = idx - k * Npad;
    dst[idx] = f2b((k < K && n < N) ? src[k * N + n] : 0.f);
}

__global__ void emb_fill_kernel(const int* __restrict__ labels, const float* __restrict__ emb,
                                unsigned short* __restrict__ fc) {
    int idx = blockIdx.x * 256 + threadIdx.x;  // 4096*32 total
    int b = idx >> 5, c = idx & 31;
    fc[b * 160 + 128 + c] = f2b(c < 16 ? emb[labels[b] * 16 + c] : 0.f);
}

// EPI: 0 = bias+relu -> bf16 ; 1 = bias -> bf16 ; 2 = fused interp/blend -> fp32 out
template<int EPI>
__global__ __launch_bounds__(256) void gemm_kernel(
    const unsigned short* __restrict__ A, const unsigned short* __restrict__ Bw,
    const float* __restrict__ bias, unsigned short* __restrict__ Cb,
    float* __restrict__ Cf, const float* __restrict__ low,
    int K, int Npad, int Nreal, int ldc)
{
    __shared__ unsigned short As[64][40];   // +8 pad breaks power-of-2 bank stride
    __shared__ unsigned short Bs[64][40];   // B stored transposed: Bs[n][k]
    const int tid = threadIdx.x;
    const int m0 = blockIdx.y * 64, n0 = blockIdx.x * 64;
    const int wave = tid >> 6, lane = tid & 63;
    const int l15 = lane & 15, g = lane >> 4;

    f32x4 acc[4] = {};

    const int ar = tid >> 2, ak = (tid & 3) << 3;   // A stage: row ar, k-chunk ak
    const int bk = tid >> 3, bn = (tid & 7) << 3;   // B stage: k-row bk, col-chunk bn
    const unsigned short* Ap = A + (size_t)(m0 + ar) * K + ak;
    const unsigned short* Bp = Bw + (size_t)bk * Npad + n0 + bn;

    const int nk = K >> 5;
    for (int kk = 0; kk < nk; ++kk) {
        u16x8 av = *reinterpret_cast<const u16x8*>(Ap);
        u16x8 bv = *reinterpret_cast<const u16x8*>(Bp);
        Ap += 32; Bp += (size_t)32 * Npad;
        *reinterpret_cast<u16x8*>(&As[ar][ak]) = av;
        #pragma unroll
        for (int j = 0; j < 8; ++j) Bs[bn + j][bk] = bv[j];
        __syncthreads();

        // A-frag: row (wave*16 + l15), k = 8*g .. 8*g+7 (same k-map for A and B
        // => result invariant to HW's internal K permutation)
        bf16x8 af = *reinterpret_cast<const bf16x8*>(&As[wave * 16 + l15][g << 3]);
        #pragma unroll
        for (int c = 0; c < 4; ++c) {
            bf16x8 bfv = *reinterpret_cast<const bf16x8*>(&Bs[c * 16 + l15][g << 3]);
            acc[c] = __builtin_amdgcn_mfma_f32_16x16x32_bf16(af, bfv, acc[c], 0, 0, 0);
        }
        __syncthreads();
    }

    // C/D layout (m89-verified): col = lane&15, row = (lane>>4)*4 + reg
    const int rbase = m0 + wave * 16 + g * 4;
    #pragma unroll
    for (int c = 0; c < 4; ++c) {
        int col = n0 + c * 16 + l15;
        if (col >= Nreal) continue;
        float bv = bias[col];
        if (EPI <= 1) {
            #pragma unroll
            for (int r = 0; r < 4; ++r) {
                float v = acc[c][r] + bv;
                if (EPI == 0) v = fmaxf(v, 0.f);
                Cb[(size_t)(rbase + r) * ldc + col] = f2b(v);
            }
        } else {
            int t = col / 6, f = col - t * 6;
            int seg = t / 20; if (seg > 98) seg = 98;
            float alpha = (float)(t - seg * 20) * 0.05f;
            bool anchor = (t - (t / 20) * 20) == 0;
            bool interior = t < 1980;
            #pragma unroll
            for (int r = 0; r < 4; ++r) {
                int row = rbase + r;
                const float* lr = low + (size_t)row * 600 + seg * 6 + f;
                float s = lr[0], e = lr[6];
                float lin = (1.f - alpha) * s + alpha * e;
                float dec = acc[c][r] + bv;
                float res = anchor ? lin : (interior ? lin + 0.2f * (dec - lin) : dec);
                Cf[(size_t)row * 12000 + col] = res;
            }
        }
    }
}

extern "C" void kernel_launch(void* const* d_in, const int* in_sizes, int n_in,
                              void* d_out, int out_size, void* d_ws, size_t ws_size,
                              hipStream_t stream) {
    const float* low = (const float*)d_in[0];
    const int*   lbl = (const int*)d_in[1];
    const float* W1 = (const float*)d_in[2];  const float* b1 = (const float*)d_in[3];
    const float* W2 = (const float*)d_in[4];  const float* b2 = (const float*)d_in[5];
    const float* W3 = (const float*)d_in[6];  const float* b3 = (const float*)d_in[7];
    const float* W4 = (const float*)d_in[8];  const float* b4 = (const float*)d_in[9];
    const float* W5 = (const float*)d_in[10]; const float* b5 = (const float*)d_in[11];
    const float* W6 = (const float*)d_in[12]; const float* b6 = (const float*)d_in[13];
    const float* emb = (const float*)d_in[14];
    float* out = (float*)d_out;

    char* ws = (char*)d_ws;
    size_t off = 0;
    auto alloc = [&](size_t elems) {
        unsigned short* p = (unsigned short*)(ws + off);
        off = (off + elems * 2 + 255) & ~(size_t)255;
        return p;
    };
    unsigned short* xb  = alloc(4096 * 608);
    unsigned short* w1b = alloc(608 * 512);
    unsigned short* w2b = alloc(512 * 256);
    unsigned short* w3b = alloc(256 * 128);
    unsigned short* w4b = alloc(160 * 256);
    unsigned short* w5b = alloc(256 * 512);
    unsigned short* w6b = alloc((size_t)512 * 12032);
    unsigned short* h1  = alloc(4096 * 512);
    unsigned short* h2  = alloc(4096 * 256);
    unsigned short* fc  = alloc(4096 * 160);
    unsigned short* h4  = alloc(4096 * 256);
    unsigned short* h5  = alloc(4096 * 512);

    auto nb = [](int total) { return dim3((unsigned)((total + 255) / 256)); };

    cast_x_kernel<<<nb(4096 * 608), 256, 0, stream>>>(low, xb);
    cast_pad_w_kernel<<<nb(608 * 512), 256, 0, stream>>>(W1, w1b, 600, 512, 512, 608 * 512);
    cast_pad_w_kernel<<<nb(512 * 256), 256, 0, stream>>>(W2, w2b, 512, 256, 256, 512 * 256);
    cast_pad_w_kernel<<<nb(256 * 128), 256, 0, stream>>>(W3, w3b, 256, 128, 128, 256 * 128);
    cast_pad_w_kernel<<<nb(160 * 256), 256, 0, stream>>>(W4, w4b, 144, 256, 256, 160 * 256);
    cast_pad_w_kernel<<<nb(256 * 512), 256, 0, stream>>>(W5, w5b, 256, 512, 512, 256 * 512);
    cast_pad_w_kernel<<<nb(512 * 12032), 256, 0, stream>>>(W6, w6b, 512, 12000, 12032, 512 * 12032);

    // L1: x(608) @ W1 -> h1 (512), relu
    gemm_kernel<0><<<dim3(8, 64), 256, 0, stream>>>(xb, w1b, b1, h1, nullptr, nullptr, 608, 512, 512, 512);
    // L2: h1(512) @ W2 -> h2 (256), relu
    gemm_kernel<0><<<dim3(4, 64), 256, 0, stream>>>(h1, w2b, b2, h2, nullptr, nullptr, 512, 256, 256, 256);
    // L3: h2(256) @ W3 -> fc[:,0:128] (ldc=160), no relu
    gemm_kernel<1><<<dim3(2, 64), 256, 0, stream>>>(h2, w3b, b3, fc, nullptr, nullptr, 256, 128, 128, 160);
    // label embedding into fc[:,128:144], zeros to 160
    emb_fill_kernel<<<nb(4096 * 32), 256, 0, stream>>>(lbl, emb, fc);
    // L4: fc(160) @ W4 -> h4 (256), relu
    gemm_kernel<0><<<dim3(4, 64), 256, 0, stream>>>(fc, w4b, b4, h4, nullptr, nullptr, 160, 256, 256, 256);
    // L5: h4(256) @ W5 -> h5 (512), relu
    gemm_kernel<0><<<dim3(8, 64), 256, 0, stream>>>(h4, w5b, b5, h5, nullptr, nullptr, 256, 512, 512, 512);
    // L6: h5(512) @ W6 + fused interp/blend epilogue -> out fp32
    gemm_kernel<2><<<dim3(188, 64), 256, 0, stream>>>(h5, w6b, b6, nullptr, out, low, 512, 12032, 12000, 0);
}

// Round 3
// 444.218 us; speedup vs baseline: 1.2200x; 1.2200x over previous
//
#include <hip/hip_runtime.h>
#include <hip/hip_bf16.h>

typedef __attribute__((ext_vector_type(8))) short bf16x8;
typedef __attribute__((ext_vector_type(4))) float f32x4;
typedef unsigned short ushort_t;
typedef unsigned int u32;

__device__ __forceinline__ ushort_t f2b(float f) {
    u32 u = __builtin_bit_cast(u32, f);
    u += 0x7FFFu + ((u >> 16) & 1u);
    return (ushort_t)(u >> 16);
}

__device__ __forceinline__ void gload_lds16(const void* g, void* l) {
    __builtin_amdgcn_global_load_lds(
        (const __attribute__((address_space(1))) u32*)g,
        (__attribute__((address_space(3))) u32*)l, 16, 0, 0);
}

// ---------------- fused transpose-cast: W [K][N] f32 -> Wt [Npad][Kpad] bf16 ----
struct TrDesc { const float* src; ushort_t* dst; int K, N, Kpad, Npad, base, nx; };
struct TrArgs { TrDesc d[6]; };

__global__ __launch_bounds__(256) void tr_cast_kernel(TrArgs a) {
    __shared__ float T[64][65];
    const int bid = blockIdx.x, tid = threadIdx.x;
    int w = 0;
    #pragma unroll
    for (int i = 1; i < 6; ++i) if (bid >= a.d[i].base) w = i;
    const TrDesc d = a.d[w];
    const int local = bid - d.base;
    const int n0 = (local % d.nx) * 64, k0 = (local / d.nx) * 64;
    #pragma unroll
    for (int it = 0; it < 16; ++it) {
        int idx = it * 256 + tid;
        int r = idx >> 6, c = idx & 63;            // r: k-offset, c: n-offset (coalesced)
        int k = k0 + r, n = n0 + c;
        T[c][r] = (k < d.K && n < d.N) ? d.src[(size_t)k * d.N + n] : 0.f;
    }
    __syncthreads();
    #pragma unroll
    for (int it = 0; it < 16; ++it) {
        int idx = it * 256 + tid;
        int r = idx >> 6, c = idx & 63;            // r: n-offset, c: k-offset (coalesced)
        int n = n0 + r, k = k0 + c;
        if (k < d.Kpad)
            d.dst[(size_t)n * d.Kpad + k] = f2b(T[r][c]);
    }
}

__global__ void cast_x_kernel(const float* __restrict__ low, ushort_t* __restrict__ dst) {
    int idx = blockIdx.x * 256 + threadIdx.x;
    if (idx >= 4096 * 608) return;
    int b = idx / 608, k = idx - b * 608;
    dst[idx] = f2b(k < 600 ? low[b * 600 + k] : 0.f);
}

__global__ void emb_fill_kernel(const int* __restrict__ labels, const float* __restrict__ emb,
                                ushort_t* __restrict__ fc) {
    int idx = blockIdx.x * 256 + threadIdx.x;  // 4096*32
    int b = idx >> 5, c = idx & 31;
    fc[b * 160 + 128 + c] = f2b(c < 16 ? emb[labels[b] * 16 + c] : 0.f);
}

// ---------------- m97-style 128x128 GEMM, BK=32, global_load_lds + XOR swizzle ---
// A [M][K] bf16 row-major, Bt [N][K] bf16 row-major. EPI: 0 relu->bf16, 1 ->bf16,
// 2 fused interp/blend -> f32.
template<int EPI>
__global__ __launch_bounds__(256) void gemm128(
    const ushort_t* __restrict__ A, const ushort_t* __restrict__ Bt,
    const float* __restrict__ bias, ushort_t* __restrict__ Cb,
    float* __restrict__ Cf, const float* __restrict__ low,
    int K, int Nreal, int ldc)
{
    __shared__ ushort_t As[128 * 32];
    __shared__ ushort_t Bs[128 * 32];
    const int tid = threadIdx.x;
    const int wave = tid >> 6, lane = tid & 63;
    const int l15 = lane & 15, g = lane >> 4;
    const int wr = wave >> 1, wc = wave & 1;
    const int m0 = blockIdx.y * 128, n0 = blockIdx.x * 128;

    f32x4 acc[4][4] = {};

    // Staging map: LDS linear byte p holds element (row = p>>6, k-chunk XOR-swizzled).
    // Swizzle: byte_inner ^= ((row>>1)&3)<<4  (involution; reader applies same XOR).
    const int p0 = tid * 16;
    const int row0 = p0 >> 6;
    const int k0s = (((p0 & 63) ^ (((row0 >> 1) & 3) << 4)) >> 1);
    const int p1 = 4096 + tid * 16;
    const int row1 = p1 >> 6;
    const int k1s = (((p1 & 63) ^ (((row1 >> 1) & 3) << 4)) >> 1);

    const ushort_t* a0 = A + (size_t)(m0 + row0) * K + k0s;
    const ushort_t* a1 = A + (size_t)(m0 + row1) * K + k1s;
    const ushort_t* b0 = Bt + (size_t)(n0 + row0) * K + k0s;
    const ushort_t* b1 = Bt + (size_t)(n0 + row1) * K + k1s;

    // wave-uniform LDS dests (bytes): i*4096 + wave*1024 (+ lane*16 by HW)
    char* AsB = (char*)As + wave * 1024;
    char* BsB = (char*)Bs + wave * 1024;

    // fragment read offsets (elements), swizzle s = ((l15>>1)&3)<<4 (row-bit part
    // is invariant across i since i*16 keeps (row>>1)&3 unchanged)
    const int sxor = ((l15 >> 1) & 3) << 4;
    const ushort_t* ardA = As + (((wr * 64 + l15) * 64 + ((g * 16) ^ sxor)) >> 1);
    const ushort_t* brdB = Bs + (((wc * 64 + l15) * 64 + ((g * 16) ^ sxor)) >> 1);

    const int nk = K >> 5;
    for (int kk = 0; kk < nk; ++kk) {
        gload_lds16(a0, AsB);
        gload_lds16(a1, AsB + 4096);
        gload_lds16(b0, BsB);
        gload_lds16(b1, BsB + 4096);
        a0 += 32; a1 += 32; b0 += 32; b1 += 32;
        __syncthreads();                 // compiler drains vmcnt before barrier

        bf16x8 af[4], bf[4];
        #pragma unroll
        for (int i = 0; i < 4; ++i) af[i] = *(const bf16x8*)(ardA + i * 512);
        #pragma unroll
        for (int j = 0; j < 4; ++j) bf[j] = *(const bf16x8*)(brdB + j * 512);
        #pragma unroll
        for (int i = 0; i < 4; ++i)
            #pragma unroll
            for (int j = 0; j < 4; ++j)
                acc[i][j] = __builtin_amdgcn_mfma_f32_16x16x32_bf16(af[i], bf[j], acc[i][j], 0, 0, 0);
        __syncthreads();
    }

    // C/D layout: col = lane&15 (B-row = n), row = (lane>>4)*4 + reg (A-row = m)
    #pragma unroll
    for (int j = 0; j < 4; ++j) {
        const int col = n0 + wc * 64 + j * 16 + l15;
        if (col >= Nreal) continue;
        const float bv = bias[col];
        if (EPI <= 1) {
            #pragma unroll
            for (int i = 0; i < 4; ++i)
                #pragma unroll
                for (int r = 0; r < 4; ++r) {
                    int row = m0 + wr * 64 + i * 16 + g * 4 + r;
                    float v = acc[i][j][r] + bv;
                    if (EPI == 0) v = fmaxf(v, 0.f);
                    Cb[(size_t)row * ldc + col] = f2b(v);
                }
        } else {
            const int t = col / 6, f = col - t * 6;
            int seg = t / 20; if (seg > 98) seg = 98;
            const float alpha = (float)(t - seg * 20) * 0.05f;
            const bool anchor = (t - (t / 20) * 20) == 0;
            const bool interior = t < 1980;
            #pragma unroll
            for (int i = 0; i < 4; ++i)
                #pragma unroll
                for (int r = 0; r < 4; ++r) {
                    int row = m0 + wr * 64 + i * 16 + g * 4 + r;
                    const float* lr = low + (size_t)row * 600 + seg * 6 + f;
                    float s = lr[0], e = lr[6];
                    float lin = (1.f - alpha) * s + alpha * e;
                    float dec = acc[i][j][r] + bv;
                    float res = anchor ? lin : (interior ? lin + 0.2f * (dec - lin) : dec);
                    Cf[(size_t)row * 12000 + col] = res;
                }
        }
    }
}

extern "C" void kernel_launch(void* const* d_in, const int* in_sizes, int n_in,
                              void* d_out, int out_size, void* d_ws, size_t ws_size,
                              hipStream_t stream) {
    const float* low = (const float*)d_in[0];
    const int*   lbl = (const int*)d_in[1];
    const float* W1 = (const float*)d_in[2];  const float* b1 = (const float*)d_in[3];
    const float* W2 = (const float*)d_in[4];  const float* b2 = (const float*)d_in[5];
    const float* W3 = (const float*)d_in[6];  const float* b3 = (const float*)d_in[7];
    const float* W4 = (const float*)d_in[8];  const float* b4 = (const float*)d_in[9];
    const float* W5 = (const float*)d_in[10]; const float* b5 = (const float*)d_in[11];
    const float* W6 = (const float*)d_in[12]; const float* b6 = (const float*)d_in[13];
    const float* emb = (const float*)d_in[14];
    float* out = (float*)d_out;

    char* ws = (char*)d_ws;
    size_t off = 0;
    auto alloc = [&](size_t elems) {
        ushort_t* p = (ushort_t*)(ws + off);
        off = (off + elems * 2 + 255) & ~(size_t)255;
        return p;
    };
    ushort_t* xb  = alloc((size_t)4096 * 608);
    ushort_t* w1t = alloc((size_t)512 * 608);
    ushort_t* w2t = alloc((size_t)256 * 512);
    ushort_t* w3t = alloc((size_t)128 * 256);
    ushort_t* w4t = alloc((size_t)256 * 160);
    ushort_t* w5t = alloc((size_t)512 * 256);
    ushort_t* w6t = alloc((size_t)12032 * 512);
    ushort_t* h1  = alloc((size_t)4096 * 512);
    ushort_t* h2  = alloc((size_t)4096 * 256);
    ushort_t* fc  = alloc((size_t)4096 * 160);
    ushort_t* h4  = alloc((size_t)4096 * 256);
    ushort_t* h5  = alloc((size_t)4096 * 512);

    // transpose-cast descriptors: {src, dst, K, N, Kpad, Npad, tile_base, nx}
    TrArgs ta;
    int base = 0;
    auto mk = [&](int i, const float* s, ushort_t* d, int K, int N, int Kp, int Np) {
        int nx = Np / 64, ny = (Kp + 63) / 64;
        ta.d[i] = TrDesc{s, d, K, N, Kp, Np, base, nx};
        base += nx * ny;
    };
    mk(0, W1, w1t, 600, 512, 608, 512);
    mk(1, W2, w2t, 512, 256, 512, 256);
    mk(2, W3, w3t, 256, 128, 256, 128);
    mk(3, W4, w4t, 144, 256, 160, 256);
    mk(4, W5, w5t, 256, 512, 256, 512);
    mk(5, W6, w6t, 512, 12000, 512, 12032);

    tr_cast_kernel<<<dim3(base), 256, 0, stream>>>(ta);
    cast_x_kernel<<<dim3((4096 * 608 + 255) / 256), 256, 0, stream>>>(low, xb);

    // L1: xb(608) @ w1t -> h1(512), relu
    gemm128<0><<<dim3(4, 32), 256, 0, stream>>>(xb, w1t, b1, h1, nullptr, nullptr, 608, 512, 512);
    // L2: h1(512) @ w2t -> h2(256), relu
    gemm128<0><<<dim3(2, 32), 256, 0, stream>>>(h1, w2t, b2, h2, nullptr, nullptr, 512, 256, 256);
    // L3: h2(256) @ w3t -> fc[:,0:128] (ldc=160)
    gemm128<1><<<dim3(1, 32), 256, 0, stream>>>(h2, w3t, b3, fc, nullptr, nullptr, 256, 128, 160);
    emb_fill_kernel<<<dim3(4096 * 32 / 256), 256, 0, stream>>>(lbl, emb, fc);
    // L4: fc(160) @ w4t -> h4(256), relu
    gemm128<0><<<dim3(2, 32), 256, 0, stream>>>(fc, w4t, b4, h4, nullptr, nullptr, 160, 256, 256);
    // L5: h4(256) @ w5t -> h5(512), relu
    gemm128<0><<<dim3(4, 32), 256, 0, stream>>>(h4, w5t, b5, h5, nullptr, nullptr, 256, 512, 512);
    // L6: h5(512) @ w6t + fused interp/blend -> out f32
    gemm128<2><<<dim3(94, 32), 256, 0, stream>>>(h5, w6t, b6, nullptr, out, low, 512, 12000, 0);
}

// Round 4
// 441.811 us; speedup vs baseline: 1.2267x; 1.0054x over previous
//
#include <hip/hip_runtime.h>
#include <hip/hip_bf16.h>

typedef __attribute__((ext_vector_type(8))) short bf16x8;
typedef __attribute__((ext_vector_type(4))) float f32x4;
typedef unsigned short ushort_t;
typedef unsigned int u32;

__device__ __forceinline__ ushort_t f2b(float f) {
    u32 u = __builtin_bit_cast(u32, f);
    u += 0x7FFFu + ((u >> 16) & 1u);
    return (ushort_t)(u >> 16);
}

__device__ __forceinline__ void gload_lds16(const void* g, void* l) {
    __builtin_amdgcn_global_load_lds(
        (const __attribute__((address_space(1))) u32*)g,
        (__attribute__((address_space(3))) u32*)l, 16, 0, 0);
}

// ---------------- fused transpose-cast: W [K][N] f32 -> Wt [Npad][Kpad] bf16 ----
struct TrDesc { const float* src; ushort_t* dst; int K, N, Kpad, Npad, base, nx; };
struct TrArgs { TrDesc d[6]; };

__global__ __launch_bounds__(256) void tr_cast_kernel(TrArgs a) {
    __shared__ float T[64][65];
    const int bid = blockIdx.x, tid = threadIdx.x;
    int w = 0;
    #pragma unroll
    for (int i = 1; i < 6; ++i) if (bid >= a.d[i].base) w = i;
    const TrDesc d = a.d[w];
    const int local = bid - d.base;
    const int n0 = (local % d.nx) * 64, k0 = (local / d.nx) * 64;
    #pragma unroll
    for (int it = 0; it < 16; ++it) {
        int idx = it * 256 + tid;
        int r = idx >> 6, c = idx & 63;
        int k = k0 + r, n = n0 + c;
        T[c][r] = (k < d.K && n < d.N) ? d.src[(size_t)k * d.N + n] : 0.f;
    }
    __syncthreads();
    #pragma unroll
    for (int it = 0; it < 16; ++it) {
        int idx = it * 256 + tid;
        int r = idx >> 6, c = idx & 63;
        int n = n0 + r, k = k0 + c;
        if (k < d.Kpad)
            d.dst[(size_t)n * d.Kpad + k] = f2b(T[r][c]);
    }
}

__global__ void cast_x_kernel(const float* __restrict__ low, ushort_t* __restrict__ dst) {
    int idx = blockIdx.x * 256 + threadIdx.x;
    if (idx >= 4096 * 608) return;
    int b = idx / 608, k = idx - b * 608;
    dst[idx] = f2b(k < 600 ? low[b * 600 + k] : 0.f);
}

__global__ void emb_fill_kernel(const int* __restrict__ labels, const float* __restrict__ emb,
                                ushort_t* __restrict__ fc) {
    int idx = blockIdx.x * 256 + threadIdx.x;  // 4096*32
    int b = idx >> 5, c = idx & 31;
    fc[b * 160 + 128 + c] = f2b(c < 16 ? emb[labels[b] * 16 + c] : 0.f);
}

// ---------------- 64x64-tile GEMM for small layers (parallelism-first) ----------
// A [M][K] bf16, Bt [N][K] bf16. EPI: 0 relu->bf16, 1 ->bf16.
template<int EPI>
__global__ __launch_bounds__(256) void gemm64(
    const ushort_t* __restrict__ A, const ushort_t* __restrict__ Bt,
    const float* __restrict__ bias, ushort_t* __restrict__ Cb,
    int K, int Nreal, int ldc)
{
    __shared__ ushort_t As[64 * 32];
    __shared__ ushort_t Bs[64 * 32];
    const int tid = threadIdx.x;
    const int wave = tid >> 6, lane = tid & 63;
    const int l15 = lane & 15, g = lane >> 4;
    const int wr = wave >> 1, wc = wave & 1;
    const int m0 = blockIdx.y * 64, n0 = blockIdx.x * 64;

    f32x4 acc[2][2] = {};

    const int p0 = tid * 16;
    const int row0 = p0 >> 6;
    const int k0s = (((p0 & 63) ^ (((row0 >> 1) & 3) << 4)) >> 1);

    const ushort_t* a0 = A + (size_t)(m0 + row0) * K + k0s;
    const ushort_t* b0 = Bt + (size_t)(n0 + row0) * K + k0s;

    char* AsB = (char*)As + wave * 1024;
    char* BsB = (char*)Bs + wave * 1024;

    const int sxor = ((l15 >> 1) & 3) << 4;
    const ushort_t* ardA = As + (((wr * 32 + l15) * 64 + ((g * 16) ^ sxor)) >> 1);
    const ushort_t* brdB = Bs + (((wc * 32 + l15) * 64 + ((g * 16) ^ sxor)) >> 1);

    const int nk = K >> 5;
    for (int kk = 0; kk < nk; ++kk) {
        gload_lds16(a0, AsB);
        gload_lds16(b0, BsB);
        a0 += 32; b0 += 32;
        __syncthreads();
        bf16x8 af[2], bf[2];
        #pragma unroll
        for (int i = 0; i < 2; ++i) af[i] = *(const bf16x8*)(ardA + i * 512);
        #pragma unroll
        for (int j = 0; j < 2; ++j) bf[j] = *(const bf16x8*)(brdB + j * 512);
        #pragma unroll
        for (int i = 0; i < 2; ++i)
            #pragma unroll
            for (int j = 0; j < 2; ++j)
                acc[i][j] = __builtin_amdgcn_mfma_f32_16x16x32_bf16(af[i], bf[j], acc[i][j], 0, 0, 0);
        __syncthreads();
    }

    // row outer, j inner => adjacent 32B segments per row
    #pragma unroll
    for (int i = 0; i < 2; ++i)
        #pragma unroll
        for (int r = 0; r < 4; ++r) {
            int row = m0 + wr * 32 + i * 16 + g * 4 + r;
            #pragma unroll
            for (int j = 0; j < 2; ++j) {
                int col = n0 + wc * 32 + j * 16 + l15;
                if (col >= Nreal) continue;
                float v = acc[i][j][r] + bias[col];
                if (EPI == 0) v = fmaxf(v, 0.f);
                Cb[(size_t)row * ldc + col] = f2b(v);
            }
        }
}

// ---------------- 128x128 GEMM for L6, fused interp/blend epilogue --------------
__global__ __launch_bounds__(256) void gemm128_l6(
    const ushort_t* __restrict__ A, const ushort_t* __restrict__ Bt,
    const float* __restrict__ bias, float* __restrict__ Cf,
    const float* __restrict__ low, int K)
{
    __shared__ ushort_t As[128 * 32];
    __shared__ ushort_t Bs[128 * 32];
    const int tid = threadIdx.x;
    const int wave = tid >> 6, lane = tid & 63;
    const int l15 = lane & 15, g = lane >> 4;
    const int wr = wave >> 1, wc = wave & 1;

    // bijective XCD swizzle (3008 blocks, 3008%8==0); m-major within XCD chunk
    const int bid = blockIdx.x;
    const int swz = (bid & 7) * 376 + (bid >> 3);
    const int m0 = (swz & 31) * 128, n0 = (swz >> 5) * 128;

    f32x4 acc[4][4] = {};

    const int p0 = tid * 16;
    const int row0 = p0 >> 6;
    const int k0s = (((p0 & 63) ^ (((row0 >> 1) & 3) << 4)) >> 1);
    const int p1 = 4096 + tid * 16;
    const int row1 = p1 >> 6;
    const int k1s = (((p1 & 63) ^ (((row1 >> 1) & 3) << 4)) >> 1);

    const ushort_t* a0 = A + (size_t)(m0 + row0) * K + k0s;
    const ushort_t* a1 = A + (size_t)(m0 + row1) * K + k1s;
    const ushort_t* b0 = Bt + (size_t)(n0 + row0) * K + k0s;
    const ushort_t* b1 = Bt + (size_t)(n0 + row1) * K + k1s;

    char* AsB = (char*)As + wave * 1024;
    char* BsB = (char*)Bs + wave * 1024;

    const int sxor = ((l15 >> 1) & 3) << 4;
    const ushort_t* ardA = As + (((wr * 64 + l15) * 64 + ((g * 16) ^ sxor)) >> 1);
    const ushort_t* brdB = Bs + (((wc * 64 + l15) * 64 + ((g * 16) ^ sxor)) >> 1);

    const int nk = K >> 5;
    for (int kk = 0; kk < nk; ++kk) {
        gload_lds16(a0, AsB);
        gload_lds16(a1, AsB + 4096);
        gload_lds16(b0, BsB);
        gload_lds16(b1, BsB + 4096);
        a0 += 32; a1 += 32; b0 += 32; b1 += 32;
        __syncthreads();

        bf16x8 af[4], bf[4];
        #pragma unroll
        for (int i = 0; i < 4; ++i) af[i] = *(const bf16x8*)(ardA + i * 512);
        #pragma unroll
        for (int j = 0; j < 4; ++j) bf[j] = *(const bf16x8*)(brdB + j * 512);
        #pragma unroll
        for (int i = 0; i < 4; ++i)
            #pragma unroll
            for (int j = 0; j < 4; ++j)
                acc[i][j] = __builtin_amdgcn_mfma_f32_16x16x32_bf16(af[i], bf[j], acc[i][j], 0, 0, 0);
        __syncthreads();
    }

    // ---- epilogue: precompute per-j column state; row outer, j inner so a wave's
    // four 64B store segments per row are program-order adjacent (full 128B lines,
    // no read-for-ownership) ----
    int colv[4]; float bvv[4]; int offv[4]; float alphav[4];
    bool anch[4], interi[4], valid[4];
    #pragma unroll
    for (int j = 0; j < 4; ++j) {
        int col = n0 + wc * 64 + j * 16 + l15;
        colv[j] = col;
        valid[j] = col < 12000;
        int cc = valid[j] ? col : 0;
        bvv[j] = bias[cc];
        int t = cc / 6, f = cc - t * 6;
        int seg = t / 20; if (seg > 98) seg = 98;
        offv[j] = seg * 6 + f;
        alphav[j] = (float)(t - seg * 20) * 0.05f;
        anch[j] = (t % 20) == 0;
        interi[j] = t < 1980;
    }
    #pragma unroll
    for (int i = 0; i < 4; ++i)
        #pragma unroll
        for (int r = 0; r < 4; ++r) {
            const int row = m0 + wr * 64 + i * 16 + g * 4 + r;
            const float* lrow = low + (size_t)row * 600;
            float* orow = Cf + (size_t)row * 12000;
            #pragma unroll
            for (int j = 0; j < 4; ++j) {
                if (!valid[j]) continue;
                float s = lrow[offv[j]], e = lrow[offv[j] + 6];
                float lin = (1.f - alphav[j]) * s + alphav[j] * e;
                float dec = acc[i][j][r] + bvv[j];
                float res = anch[j] ? lin : (interi[j] ? lin + 0.2f * (dec - lin) : dec);
                orow[colv[j]] = res;
            }
        }
}

extern "C" void kernel_launch(void* const* d_in, const int* in_sizes, int n_in,
                              void* d_out, int out_size, void* d_ws, size_t ws_size,
                              hipStream_t stream) {
    const float* low = (const float*)d_in[0];
    const int*   lbl = (const int*)d_in[1];
    const float* W1 = (const float*)d_in[2];  const float* b1 = (const float*)d_in[3];
    const float* W2 = (const float*)d_in[4];  const float* b2 = (const float*)d_in[5];
    const float* W3 = (const float*)d_in[6];  const float* b3 = (const float*)d_in[7];
    const float* W4 = (const float*)d_in[8];  const float* b4 = (const float*)d_in[9];
    const float* W5 = (const float*)d_in[10]; const float* b5 = (const float*)d_in[11];
    const float* W6 = (const float*)d_in[12]; const float* b6 = (const float*)d_in[13];
    const float* emb = (const float*)d_in[14];
    float* out = (float*)d_out;

    char* ws = (char*)d_ws;
    size_t off = 0;
    auto alloc = [&](size_t elems) {
        ushort_t* p = (ushort_t*)(ws + off);
        off = (off + elems * 2 + 255) & ~(size_t)255;
        return p;
    };
    ushort_t* xb  = alloc((size_t)4096 * 608);
    ushort_t* w1t = alloc((size_t)512 * 608);
    ushort_t* w2t = alloc((size_t)256 * 512);
    ushort_t* w3t = alloc((size_t)128 * 256);
    ushort_t* w4t = alloc((size_t)256 * 160);
    ushort_t* w5t = alloc((size_t)512 * 256);
    ushort_t* w6t = alloc((size_t)12032 * 512);
    ushort_t* h1  = alloc((size_t)4096 * 512);
    ushort_t* h2  = alloc((size_t)4096 * 256);
    ushort_t* fc  = alloc((size_t)4096 * 160);
    ushort_t* h4  = alloc((size_t)4096 * 256);
    ushort_t* h5  = alloc((size_t)4096 * 512);

    TrArgs ta;
    int base = 0;
    auto mk = [&](int i, const float* s, ushort_t* d, int K, int N, int Kp, int Np) {
        int nx = Np / 64, ny = (Kp + 63) / 64;
        ta.d[i] = TrDesc{s, d, K, N, Kp, Np, base, nx};
        base += nx * ny;
    };
    mk(0, W1, w1t, 600, 512, 608, 512);
    mk(1, W2, w2t, 512, 256, 512, 256);
    mk(2, W3, w3t, 256, 128, 256, 128);
    mk(3, W4, w4t, 144, 256, 160, 256);
    mk(4, W5, w5t, 256, 512, 256, 512);
    mk(5, W6, w6t, 512, 12000, 512, 12032);

    tr_cast_kernel<<<dim3(base), 256, 0, stream>>>(ta);
    cast_x_kernel<<<dim3((4096 * 608 + 255) / 256), 256, 0, stream>>>(low, xb);

    // L1: xb(608) @ w1t -> h1(512), relu          [512 blocks]
    gemm64<0><<<dim3(8, 64), 256, 0, stream>>>(xb, w1t, b1, h1, 608, 512, 512);
    // L2: h1(512) @ w2t -> h2(256), relu          [256 blocks]
    gemm64<0><<<dim3(4, 64), 256, 0, stream>>>(h1, w2t, b2, h2, 512, 256, 256);
    // L3: h2(256) @ w3t -> fc[:,0:128] (ldc=160)  [128 blocks]
    gemm64<1><<<dim3(2, 64), 256, 0, stream>>>(h2, w3t, b3, fc, 256, 128, 160);
    emb_fill_kernel<<<dim3(4096 * 32 / 256), 256, 0, stream>>>(lbl, emb, fc);
    // L4: fc(160) @ w4t -> h4(256), relu          [256 blocks]
    gemm64<0><<<dim3(4, 64), 256, 0, stream>>>(fc, w4t, b4, h4, 160, 256, 256);
    // L5: h4(256) @ w5t -> h5(512), relu          [512 blocks]
    gemm64<0><<<dim3(8, 64), 256, 0, stream>>>(h4, w5t, b5, h5, 256, 512, 512);
    // L6: h5(512) @ w6t + fused interp/blend -> out f32   [3008 blocks, XCD swz]
    gemm128_l6<<<dim3(3008), 256, 0, stream>>>(h5, w6t, b6, out, low, 512);
}

// Round 6
// 392.002 us; speedup vs baseline: 1.3825x; 1.1271x over previous
//
#include <hip/hip_runtime.h>
#include <hip/hip_bf16.h>

typedef __attribute__((ext_vector_type(8))) short bf16x8;
typedef __attribute__((ext_vector_type(4))) float f32x4;
typedef __attribute__((ext_vector_type(8))) unsigned short u16x8;
typedef unsigned short ushort_t;
typedef unsigned int u32;

__device__ __forceinline__ ushort_t f2b(float f) {
    u32 u = __builtin_bit_cast(u32, f);
    u += 0x7FFFu + ((u >> 16) & 1u);
    return (ushort_t)(u >> 16);
}

__device__ __forceinline__ void gload_lds16(const void* g, void* l) {
    __builtin_amdgcn_global_load_lds(
        (const __attribute__((address_space(1))) u32*)g,
        (__attribute__((address_space(3))) u32*)l, 16, 0, 0);
}

// ------------- prep kernel: 6x transpose-cast W -> Wt, plus x cast-pad ---------
struct TrDesc { const float* src; ushort_t* dst; int K, N, Kpad, Npad, base, nx; };
struct TrArgs { TrDesc d[6]; const float* low; ushort_t* xb; int trbase; };

__global__ __launch_bounds__(256) void prep_kernel(TrArgs a) {
    const int bid = blockIdx.x, tid = threadIdx.x;
    if (bid >= a.trbase) {
        // cast x: low [4096][600] f32 -> xb [4096][608] bf16 (zero pad)
        int idx = (bid - a.trbase) * 256 + tid;          // 0..311295
        int b = idx / 76, c = idx - b * 76;
        ushort_t* dp = a.xb + (size_t)b * 608 + c * 8;
        u16x8 o;
        if (c < 75) {
            const float* sp = a.low + (size_t)b * 600 + c * 8;
            f32x4 v0 = *(const f32x4*)sp, v1 = *(const f32x4*)(sp + 4);
            #pragma unroll
            for (int j = 0; j < 4; ++j) { o[j] = f2b(v0[j]); o[4 + j] = f2b(v1[j]); }
        } else {
            #pragma unroll
            for (int j = 0; j < 8; ++j) o[j] = 0;
        }
        *(u16x8*)dp = o;
        return;
    }
    __shared__ float T[64][65];
    int w = 0;
    #pragma unroll
    for (int i = 1; i < 6; ++i) if (bid >= a.d[i].base) w = i;
    const TrDesc d = a.d[w];
    const int local = bid - d.base;
    const int n0 = (local % d.nx) * 64, k0 = (local / d.nx) * 64;
    #pragma unroll
    for (int it = 0; it < 16; ++it) {
        int idx = it * 256 + tid;
        int r = idx >> 6, c = idx & 63;
        int k = k0 + r, n = n0 + c;
        T[c][r] = (k < d.K && n < d.N) ? d.src[(size_t)k * d.N + n] : 0.f;
    }
    __syncthreads();
    #pragma unroll
    for (int it = 0; it < 16; ++it) {
        int idx = it * 256 + tid;
        int r = idx >> 6, c = idx & 63;
        int n = n0 + r, k = k0 + c;
        if (k < d.Kpad)
            d.dst[(size_t)n * d.Kpad + k] = f2b(T[r][c]);
    }
}

// ------------- 64x64 GEMM, double-buffered 2-phase. EPI: 0 relu, 1 none(+emb) --
template<int EPI>
__global__ __launch_bounds__(256, 4) void gemm64(
    const ushort_t* __restrict__ A, const ushort_t* __restrict__ Bt,
    const float* __restrict__ bias, ushort_t* __restrict__ Cb,
    const int* __restrict__ lbl, const float* __restrict__ emb,
    int K, int Nreal, int ldc)
{
    __shared__ ushort_t As[2][64 * 32];   // 4KB per buf
    __shared__ ushort_t Bs[2][64 * 32];
    const int tid = threadIdx.x;
    const int wave = tid >> 6, lane = tid & 63;
    const int l15 = lane & 15, g = lane >> 4;
    const int wr = wave >> 1, wc = wave & 1;
    const int m0 = blockIdx.y * 64, n0 = blockIdx.x * 64;

    f32x4 acc[2][2] = {};

    const int p0 = tid * 16;
    const int row0 = p0 >> 6;
    const int k0s = (((p0 & 63) ^ (((row0 >> 1) & 3) << 4)) >> 1);
    const ushort_t* a0 = A + (size_t)(m0 + row0) * K + k0s;
    const ushort_t* b0 = Bt + (size_t)(n0 + row0) * K + k0s;

    char* AsB = (char*)As + wave * 1024;
    char* BsB = (char*)Bs + wave * 1024;

    const int sxor = ((l15 >> 1) & 3) << 4;
    const ushort_t* ardA = &As[0][0] + (((wr * 32 + l15) * 64 + ((g * 16) ^ sxor)) >> 1);
    const ushort_t* brdB = &Bs[0][0] + (((wc * 32 + l15) * 64 + ((g * 16) ^ sxor)) >> 1);

    const int nk = K >> 5;
    gload_lds16(a0, AsB); gload_lds16(b0, BsB);
    a0 += 32; b0 += 32;
    __syncthreads();
    #pragma unroll 2
    for (int kk = 0; kk < nk; ++kk) {
        const int cur = kk & 1, nxt = cur ^ 1;
        if (kk + 1 < nk) {
            gload_lds16(a0, AsB + nxt * 4096);
            gload_lds16(b0, BsB + nxt * 4096);
            a0 += 32; b0 += 32;
        }
        bf16x8 af[2], bf[2];
        #pragma unroll
        for (int i = 0; i < 2; ++i) af[i] = *(const bf16x8*)(ardA + cur * 2048 + i * 512);
        #pragma unroll
        for (int j = 0; j < 2; ++j) bf[j] = *(const bf16x8*)(brdB + cur * 2048 + j * 512);
        #pragma unroll
        for (int i = 0; i < 2; ++i)
            #pragma unroll
            for (int j = 0; j < 2; ++j)
                acc[i][j] = __builtin_amdgcn_mfma_f32_16x16x32_bf16(af[i], bf[j], acc[i][j], 0, 0, 0);
        __syncthreads();
    }

    #pragma unroll
    for (int i = 0; i < 2; ++i)
        #pragma unroll
        for (int r = 0; r < 4; ++r) {
            int row = m0 + wr * 32 + i * 16 + g * 4 + r;
            #pragma unroll
            for (int j = 0; j < 2; ++j) {
                int col = n0 + wc * 32 + j * 16 + l15;
                if (col >= Nreal) continue;
                float v = acc[i][j][r] + bias[col];
                if (EPI == 0) v = fmaxf(v, 0.f);
                Cb[(size_t)row * ldc + col] = f2b(v);
            }
        }

    // fused label-embedding fill (L3 only): cols 128..159 of fc for rows m0..m0+63
    if (EPI == 1 && blockIdx.x == 0) {
        #pragma unroll
        for (int q = 0; q < 8; ++q) {
            int e = tid + q * 256;               // 0..2047
            int row = m0 + (e >> 5), c = e & 31;
            float v = c < 16 ? emb[(size_t)lbl[row] * 16 + c] : 0.f;
            Cb[(size_t)row * ldc + 128 + c] = f2b(v);
        }
    }
}

// ------------- 128x128 GEMM for L6, dbuf 2-phase + fused epilogue + nt stores --
__global__ __launch_bounds__(256, 4) void gemm128_l6(
    const ushort_t* __restrict__ A, const ushort_t* __restrict__ Bt,
    const float* __restrict__ bias, float* __restrict__ Cf,
    const float* __restrict__ low, int K)
{
    __shared__ ushort_t As[2][128 * 32];   // 8KB per buf
    __shared__ ushort_t Bs[2][128 * 32];
    const int tid = threadIdx.x;
    const int wave = tid >> 6, lane = tid & 63;
    const int l15 = lane & 15, g = lane >> 4;
    const int wr = wave >> 1, wc = wave & 1;
    const int m0 = blockIdx.y * 128, n0 = blockIdx.x * 128;

    f32x4 acc[4][4] = {};

    const int p0 = tid * 16;
    const int row0 = p0 >> 6;
    const int k0s = (((p0 & 63) ^ (((row0 >> 1) & 3) << 4)) >> 1);
    const int p1 = 4096 + tid * 16;
    const int row1 = p1 >> 6;
    const int k1s = (((p1 & 63) ^ (((row1 >> 1) & 3) << 4)) >> 1);

    const ushort_t* a0 = A + (size_t)(m0 + row0) * K + k0s;
    const ushort_t* a1 = A + (size_t)(m0 + row1) * K + k1s;
    const ushort_t* b0 = Bt + (size_t)(n0 + row0) * K + k0s;
    const ushort_t* b1 = Bt + (size_t)(n0 + row1) * K + k1s;

    char* AsB = (char*)As + wave * 1024;
    char* BsB = (char*)Bs + wave * 1024;

    const int sxor = ((l15 >> 1) & 3) << 4;
    const ushort_t* ardA = &As[0][0] + (((wr * 64 + l15) * 64 + ((g * 16) ^ sxor)) >> 1);
    const ushort_t* brdB = &Bs[0][0] + (((wc * 64 + l15) * 64 + ((g * 16) ^ sxor)) >> 1);

    const int nk = K >> 5;   // 16
    gload_lds16(a0, AsB); gload_lds16(a1, AsB + 4096);
    gload_lds16(b0, BsB); gload_lds16(b1, BsB + 4096);
    a0 += 32; a1 += 32; b0 += 32; b1 += 32;
    __syncthreads();
    #pragma unroll 2
    for (int kk = 0; kk < nk; ++kk) {
        const int cur = kk & 1, nxt = cur ^ 1;
        if (kk + 1 < nk) {
            gload_lds16(a0, AsB + nxt * 8192);
            gload_lds16(a1, AsB + nxt * 8192 + 4096);
            gload_lds16(b0, BsB + nxt * 8192);
            gload_lds16(b1, BsB + nxt * 8192 + 4096);
            a0 += 32; a1 += 32; b0 += 32; b1 += 32;
        }
        bf16x8 af[4], bf[4];
        #pragma unroll
        for (int i = 0; i < 4; ++i) af[i] = *(const bf16x8*)(ardA + cur * 4096 + i * 512);
        #pragma unroll
        for (int j = 0; j < 4; ++j) bf[j] = *(const bf16x8*)(brdB + cur * 4096 + j * 512);
        #pragma unroll
        for (int i = 0; i < 4; ++i)
            #pragma unroll
            for (int j = 0; j < 4; ++j)
                acc[i][j] = __builtin_amdgcn_mfma_f32_16x16x32_bf16(af[i], bf[j], acc[i][j], 0, 0, 0);
        __syncthreads();
    }

    // epilogue: per-j column state; row outer, j inner (adjacent store segments);
    // non-temporal stores keep the 192MB output stream out of L2/L3.
    float bvv[4]; int offv[4]; float alphav[4];
    bool anch[4], interi[4], valid[4];
    #pragma unroll
    for (int j = 0; j < 4; ++j) {
        int col = n0 + wc * 64 + j * 16 + l15;
        valid[j] = col < 12000;
        int cc = valid[j] ? col : 0;
        bvv[j] = bias[cc];
        int t = cc / 6, f = cc - t * 6;
        int seg = t / 20; if (seg > 98) seg = 98;
        offv[j] = seg * 6 + f;
        alphav[j] = (float)(t - seg * 20) * 0.05f;
        anch[j] = (t % 20) == 0;
        interi[j] = t < 1980;
    }
    const int colb = n0 + wc * 64 + l15;
    #pragma unroll
    for (int i = 0; i < 4; ++i)
        #pragma unroll
        for (int r = 0; r < 4; ++r) {
            const int row = m0 + wr * 64 + i * 16 + g * 4 + r;
            const float* lrow = low + (size_t)row * 600;
            float* orow = Cf + (size_t)row * 12000;
            #pragma unroll
            for (int j = 0; j < 4; ++j) {
                if (!valid[j]) continue;
                float s = lrow[offv[j]], e = lrow[offv[j] + 6];
                float lin = (1.f - alphav[j]) * s + alphav[j] * e;
                float dec = acc[i][j][r] + bvv[j];
                float res = anch[j] ? lin : (interi[j] ? lin + 0.2f * (dec - lin) : dec);
                __builtin_nontemporal_store(res, &orow[colb + j * 16]);
            }
        }
}

extern "C" void kernel_launch(void* const* d_in, const int* in_sizes, int n_in,
                              void* d_out, int out_size, void* d_ws, size_t ws_size,
                              hipStream_t stream) {
    const float* low = (const float*)d_in[0];
    const int*   lbl = (const int*)d_in[1];
    const float* W1 = (const float*)d_in[2];  const float* b1 = (const float*)d_in[3];
    const float* W2 = (const float*)d_in[4];  const float* b2 = (const float*)d_in[5];
    const float* W3 = (const float*)d_in[6];  const float* b3 = (const float*)d_in[7];
    const float* W4 = (const float*)d_in[8];  const float* b4 = (const float*)d_in[9];
    const float* W5 = (const float*)d_in[10]; const float* b5 = (const float*)d_in[11];
    const float* W6 = (const float*)d_in[12]; const float* b6 = (const float*)d_in[13];
    const float* emb = (const float*)d_in[14];
    float* out = (float*)d_out;

    char* ws = (char*)d_ws;
    size_t off = 0;
    auto alloc = [&](size_t elems) {
        ushort_t* p = (ushort_t*)(ws + off);
        off = (off + elems * 2 + 255) & ~(size_t)255;
        return p;
    };
    ushort_t* xb  = alloc((size_t)4096 * 608);
    ushort_t* w1t = alloc((size_t)512 * 608);
    ushort_t* w2t = alloc((size_t)256 * 512);
    ushort_t* w3t = alloc((size_t)128 * 256);
    ushort_t* w4t = alloc((size_t)256 * 160);
    ushort_t* w5t = alloc((size_t)512 * 256);
    ushort_t* w6t = alloc((size_t)12032 * 512);
    ushort_t* h1  = alloc((size_t)4096 * 512);
    ushort_t* h2  = alloc((size_t)4096 * 256);
    ushort_t* fc  = alloc((size_t)4096 * 160);
    ushort_t* h4  = alloc((size_t)4096 * 256);
    ushort_t* h5  = alloc((size_t)4096 * 512);

    TrArgs ta;
    int base = 0;
    auto mk = [&](int i, const float* s, ushort_t* d, int K, int N, int Kp, int Np) {
        int nx = Np / 64, ny = (Kp + 63) / 64;
        ta.d[i] = TrDesc{s, d, K, N, Kp, Np, base, nx};
        base += nx * ny;
    };
    mk(0, W1, w1t, 600, 512, 608, 512);
    mk(1, W2, w2t, 512, 256, 512, 256);
    mk(2, W3, w3t, 256, 128, 256, 128);
    mk(3, W4, w4t, 144, 256, 160, 256);
    mk(4, W5, w5t, 256, 512, 256, 512);
    mk(5, W6, w6t, 512, 12000, 512, 12032);
    ta.low = low; ta.xb = xb; ta.trbase = base;
    const int castx_blocks = (4096 * 76) / 256;   // 1216

    prep_kernel<<<dim3(base + castx_blocks), 256, 0, stream>>>(ta);

    // L1: xb(608) @ w1t -> h1(512), relu          [512 blocks]
    gemm64<0><<<dim3(8, 64), 256, 0, stream>>>(xb, w1t, b1, h1, nullptr, nullptr, 608, 512, 512);
    // L2: h1(512) @ w2t -> h2(256), relu          [256 blocks]
    gemm64<0><<<dim3(4, 64), 256, 0, stream>>>(h1, w2t, b2, h2, nullptr, nullptr, 512, 256, 256);
    // L3: h2(256) @ w3t -> fc[:,0:128] + emb fill [128 blocks]
    gemm64<1><<<dim3(2, 64), 256, 0, stream>>>(h2, w3t, b3, fc, lbl, emb, 256, 128, 160);
    // L4: fc(160) @ w4t -> h4(256), relu          [256 blocks]
    gemm64<0><<<dim3(4, 64), 256, 0, stream>>>(fc, w4t, b4, h4, nullptr, nullptr, 160, 256, 256);
    // L5: h4(256) @ w5t -> h5(512), relu          [512 blocks]
    gemm64<0><<<dim3(8, 64), 256, 0, stream>>>(h4, w5t, b5, h5, nullptr, nullptr, 256, 512, 512);
    // L6: h5(512) @ w6t + fused interp/blend -> out f32   [94x32 blocks]
    gemm128_l6<<<dim3(94, 32), 256, 0, stream>>>(h5, w6t, b6, out, low, 512);
}